// Round 6
// baseline (164.264 us; speedup 1.0000x reference)
//
#include <hip/hip_runtime.h>
#include <hip/hip_bf16.h>
#include <cstdint>
#include <cstddef>
#include <math.h>

#define D 256
#define TEMP_INV 2.0f       // 1 / TEMPERATURE, TEMPERATURE = 0.5
#define EPS_NORM 1e-8f
#define NTILES 2080         // 64*65/2 upper-triangular 128x128 tiles

typedef __attribute__((ext_vector_type(8))) short bf16x8;
typedef __attribute__((ext_vector_type(4))) float f32x4;

// ---------------- kernel 1: normalize rows, write bf16 zn ----------------
__global__ void __launch_bounds__(256) normalize_rows(
    const float* __restrict__ zi, const float* __restrict__ zj,
    __hip_bfloat16* __restrict__ zn, float* __restrict__ denom, int B) {
  int row = blockIdx.x * 4 + (threadIdx.x >> 6);
  int lane = threadIdx.x & 63;
  if (threadIdx.x < 4) denom[blockIdx.x * 4 + threadIdx.x] = 0.0f;
  const float* src = (row < B) ? (zi + (size_t)row * D)
                               : (zj + (size_t)(row - B) * D);
  float4 v = ((const float4*)src)[lane];
  float ss = v.x * v.x + v.y * v.y + v.z * v.z + v.w * v.w;
  for (int off = 32; off; off >>= 1) ss += __shfl_xor(ss, off);
  float rn = 1.0f / fmaxf(sqrtf(ss), EPS_NORM);
  union { ushort4 u; __hip_bfloat16 h[4]; } o;
  o.h[0] = __float2bfloat16(v.x * rn);
  o.h[1] = __float2bfloat16(v.y * rn);
  o.h[2] = __float2bfloat16(v.z * rn);
  o.h[3] = __float2bfloat16(v.w * rn);
  ((ushort4*)zn)[(size_t)row * (D / 4) + lane] = o.u;
}

// ---------------- kernel 2: fused sim GEMM + exp + masked row/col sums ---
// Upper-triangular 128x128 tiles, one-shot 2080 blocks, BK=64.
// Staging: lane-sequential float4 global loads (coalesced -> 64B+ L2
// requests) then ds_write_b128 with XOR swizzle on the LDS ADDRESS
// (per-lane scatter is legal for ds_write). LDS(r,c') = global chunk
// c'^(r&7) => all ds_read_b128 fragments conflict-free (0 confl @ round 4).
// Next slab's loads issue before compute (32 transient VGPRs only).
__device__ __forceinline__ void decode_tile(int t, int Nb, int& by, int& bx) {
  float fb = (2.0f * Nb + 1.0f -
              sqrtf((float)((2 * Nb + 1) * (2 * Nb + 1) - 8 * t))) * 0.5f;
  int y = (int)fb;
  while ((y + 1) * Nb - ((y + 1) * y) / 2 <= t) ++y;
  while (y * Nb - (y * (y - 1)) / 2 > t) --y;
  by = y;
  bx = y + (t - (y * Nb - (y * (y - 1)) / 2));
}

__global__ void __launch_bounds__(256, 3) ntxent_gemm(
    const __hip_bfloat16* __restrict__ zn,
    float* __restrict__ denom, float* __restrict__ pos, int B) {
  __shared__ __align__(16) __hip_bfloat16 Ash[128 * 64];  // 16 KB
  __shared__ __align__(16) __hip_bfloat16 Bsh[128 * 64];  // 16 KB

  const int Nb = (2 * B) / 128;  // 64
  int by, bx;
  decode_tile(blockIdx.x, Nb, by, bx);
  const int bm = by * 128;
  const int bn = bx * 128;
  const bool isDiag = (by == bx);
  const bool isPos = (bx == by + B / 128);

  const int tid = threadIdx.x;
  const int wid = tid >> 6;
  const int lane = tid & 63;
  const int wy = wid >> 1, wx = wid & 1;
  const int wrow0 = wid * 32;

  const int r8 = lane >> 3;     // row within 8-row staging group
  const int c8 = lane & 7;      // 16B chunk (global order: coalesced)

  const int frow = lane & 15;
  const int quad = lane >> 4;
  const int f7 = frow & 7;

  f32x4 acc[4][4] = {};
  float4 va[4], vb[4];

  // prologue: load slab 0 (lane-sequential within each 128B row segment)
#pragma unroll
  for (int s = 0; s < 4; ++s) {
    int r = wrow0 + s * 8 + r8;
    va[s] = *(const float4*)(zn + (size_t)(bm + r) * D + c8 * 8);
    vb[s] = *(const float4*)(zn + (size_t)(bn + r) * D + c8 * 8);
  }

#pragma unroll
  for (int k0i = 0; k0i < 4; ++k0i) {
    __syncthreads();  // WAR: previous slab's LDS reads complete
#pragma unroll
    for (int s = 0; s < 4; ++s) {
      int r = wrow0 + s * 8 + r8;
      int swz = c8 ^ (r & 7);
      *(float4*)&Ash[r * 64 + swz * 8] = va[s];
      *(float4*)&Bsh[r * 64 + swz * 8] = vb[s];
    }
    __syncthreads();
    if (k0i < 3) {  // issue next slab's loads; latency hides under compute
      const int k0n = (k0i + 1) * 64;
#pragma unroll
      for (int s = 0; s < 4; ++s) {
        int r = wrow0 + s * 8 + r8;
        va[s] = *(const float4*)(zn + (size_t)(bm + r) * D + k0n + c8 * 8);
        vb[s] = *(const float4*)(zn + (size_t)(bn + r) * D + k0n + c8 * 8);
      }
    }
#pragma unroll
    for (int kk = 0; kk < 2; ++kk) {
      bf16x8 a[4], b[4];
#pragma unroll
      for (int i = 0; i < 4; ++i)
        a[i] = *(const bf16x8*)
            &Ash[(wy * 64 + i * 16 + frow) * 64 + ((kk * 4 + quad) ^ f7) * 8];
#pragma unroll
      for (int j = 0; j < 4; ++j)
        b[j] = *(const bf16x8*)
            &Bsh[(wx * 64 + j * 16 + frow) * 64 + ((kk * 4 + quad) ^ f7) * 8];
#pragma unroll
      for (int i = 0; i < 4; ++i)
#pragma unroll
        for (int j = 0; j < 4; ++j)
          acc[i][j] =
              __builtin_amdgcn_mfma_f32_16x16x32_bf16(a[i], b[j], acc[i][j], 0, 0, 0);
    }
  }

  // epilogue: C/D layout col = lane&15, row = quad*4 + reg
  const int colq = lane & 15;
  float cs[4] = {0.0f, 0.0f, 0.0f, 0.0f};
#pragma unroll
  for (int i = 0; i < 4; ++i) {
#pragma unroll
    for (int r = 0; r < 4; ++r) {
      int row = bm + wy * 64 + i * 16 + quad * 4 + r;
      float rs = 0.0f;
#pragma unroll
      for (int j = 0; j < 4; ++j) {
        int col = bn + wx * 64 + j * 16 + colq;
        float v = acc[i][j][r];
        float e = __expf(v * TEMP_INV);
        e = (isDiag && col == row) ? 0.0f : e;
        rs += e;
        cs[j] += e;
        if (isPos && col == row + B) { pos[row] = v; pos[col] = v; }
      }
      rs += __shfl_xor(rs, 1);
      rs += __shfl_xor(rs, 2);
      rs += __shfl_xor(rs, 4);
      rs += __shfl_xor(rs, 8);
      if (colq == 0) atomicAdd(&denom[row], rs);
    }
  }
  if (!isDiag) {
#pragma unroll
    for (int j = 0; j < 4; ++j) {
      float c = cs[j];
      c += __shfl_xor(c, 16);
      c += __shfl_xor(c, 32);
      if (quad == 0) atomicAdd(&denom[bn + wx * 64 + j * 16 + colq], c);
    }
  }
}

// ---------------- kernel 3: finalize loss scalar -------------------------
__global__ void __launch_bounds__(1024) finalize(
    const float* __restrict__ denom, const float* __restrict__ pos,
    float* __restrict__ out, int N) {
  __shared__ float red[16];
  const int tid = threadIdx.x;
  float s = 0.0f;
  for (int i = tid; i < N / 4; i += 1024) {
    float4 d = ((const float4*)denom)[i];
    float4 p = ((const float4*)pos)[i];
    s += __logf(d.x) - p.x * TEMP_INV;
    s += __logf(d.y) - p.y * TEMP_INV;
    s += __logf(d.z) - p.z * TEMP_INV;
    s += __logf(d.w) - p.w * TEMP_INV;
  }
  for (int off = 32; off; off >>= 1) s += __shfl_xor(s, off);
  if ((tid & 63) == 0) red[tid >> 6] = s;
  __syncthreads();
  if (tid < 16) {
    s = red[tid];
    s += __shfl_xor(s, 1);
    s += __shfl_xor(s, 2);
    s += __shfl_xor(s, 4);
    s += __shfl_xor(s, 8);
    if (tid == 0) out[0] = s / (float)N;
  }
}

extern "C" void kernel_launch(void* const* d_in, const int* in_sizes, int n_in,
                              void* d_out, int out_size, void* d_ws, size_t ws_size,
                              hipStream_t stream) {
  const float* zi = (const float*)d_in[0];
  const float* zj = (const float*)d_in[1];
  const int B = in_sizes[0] / D;  // 4096
  const int N = 2 * B;            // 8192

  __hip_bfloat16* zn = (__hip_bfloat16*)d_ws;
  float* denom = (float*)((char*)d_ws + (size_t)N * D * sizeof(__hip_bfloat16));
  float* pos = denom + N;

  normalize_rows<<<N / 4, 256, 0, stream>>>(zi, zj, zn, denom, B);
  ntxent_gemm<<<NTILES, 256, 0, stream>>>(zn, denom, pos, B);
  finalize<<<1, 1024, 0, stream>>>(denom, pos, (float*)d_out, N);
}